// Round 21
// baseline (46.683 us; speedup 1.0000x reference)
//
#include <hip/hip_runtime.h>

// VectorQuantizer: fused (pack + fp16-MFMA filter + exact fp32 rescore).
// z_e [16,1024,256] f32, codebook [1024,256] f32
// out = concat( z_q [16,1024,256] f32 , indices [16,1024] as f32 )
//
// R21 = R19 EXACT (best measured, 30.3us) with grid doubled for DIAGNOSIS:
// blocks 256..511 redo blocks 0..255 identically (byte-identical writes,
// deterministic). Single dispatch ~2x duration -> exceeds the poison-fill
// top-5 cutoff -> first rocprof counters for the fused kernel since R6.
// VGPR_Count / WRITE_SIZE / VALUBusy / Occupancy will disambiguate
// {register-spill, VALU-bound, latency-structural}.
//
//  * 256-effective blocks x 1024 thr (16 waves/CU), 64 rows/block, 40 KB LDS.
//  * P1 stages -z as fp16 fragments direct from global.
//  * MFMA acc init = +0.5*csq[col] -> acc = 0.5*score >= 0 ->
//    key = (bits(acc) & ~1023) | idx; top-2 via v_min/v_max networks.
//  * P3 early-exit: margin (half-scale) > 0.08 -> winner provably exact.
//  * __launch_bounds__(1024) ONLY — arg2 clamps VGPR to 64 (measured).

#define M_ROWS 16384
#define DDIM   256
#define NCODES 1024

typedef _Float16 half8 __attribute__((ext_vector_type(8)));
typedef float    f32x4 __attribute__((ext_vector_type(4)));

__device__ __forceinline__ unsigned umin2(unsigned a, unsigned b) { return a < b ? a : b; }
__device__ __forceinline__ unsigned umax2(unsigned a, unsigned b) { return a > b ? a : b; }
__device__ __forceinline__ void top2_merge(unsigned& k0, unsigned& k1,
                                           unsigned o0, unsigned o1) {
    const unsigned t = umax2(k0, o0);
    k0 = umin2(k0, o0);
    k1 = umin2(t, umin2(k1, o1));
}

#define DPP_SELF(k, ctrl) \
    ((unsigned)__builtin_amdgcn_update_dpp((int)(k), (int)(k), (ctrl), 0xF, 0xF, false))
#define DPP_Z(v, ctrl) \
    __builtin_amdgcn_update_dpp(0, (v), (ctrl), 0xF, 0xF, true)

// 64-lane sum via DPP; total valid in lane 63
__device__ __forceinline__ float dpp_radd(float x) {
    float s = x;
    s += __int_as_float(DPP_Z(__float_as_int(s), 0x111));
    s += __int_as_float(DPP_Z(__float_as_int(s), 0x112));
    s += __int_as_float(DPP_Z(__float_as_int(s), 0x114));
    s += __int_as_float(DPP_Z(__float_as_int(s), 0x118));
    s += __int_as_float(DPP_Z(__float_as_int(s), 0x142));
    s += __int_as_float(DPP_Z(__float_as_int(s), 0x143));
    return s;
}

// ---------------- K1: pack cb (blocks 0..127) + csq (blocks 128..383) ------
__global__ __launch_bounds__(256) void vq_prep_cb(const float* __restrict__ cb,
                                                  _Float16* __restrict__ chp,
                                                  float* __restrict__ csq) {
    if (blockIdx.x < 128) {
        const int gid = blockIdx.x * 256 + threadIdx.x;
        const int l   = gid & 63;
        const int g   = gid >> 6;
        const int kt  = g & 7;
        const int rt  = g >> 3;
        const int row = rt * 16 + (l & 15);
        const int k0  = kt * 32 + (l >> 4) * 8;
        const float4 v0 = *reinterpret_cast<const float4*>(cb + (size_t)row * DDIM + k0);
        const float4 v1 = *reinterpret_cast<const float4*>(cb + (size_t)row * DDIM + k0 + 4);
        half8 h;
        h[0] = (_Float16)v0.x; h[1] = (_Float16)v0.y; h[2] = (_Float16)v0.z; h[3] = (_Float16)v0.w;
        h[4] = (_Float16)v1.x; h[5] = (_Float16)v1.y; h[6] = (_Float16)v1.z; h[7] = (_Float16)v1.w;
        *reinterpret_cast<half8*>(chp + (size_t)gid * 8) = h;
    } else {
        const int code = (blockIdx.x - 128) * 4 + (threadIdx.x >> 6);
        const int lane = threadIdx.x & 63;
        const float4 v = *reinterpret_cast<const float4*>(cb + (size_t)code * DDIM + lane * 4);
        float s = v.x * v.x + v.y * v.y + v.z * v.z + v.w * v.w;
        s = dpp_radd(s);
        if (lane == 63) csq[code] = s;
    }
}

// ---------------- K2: fused pack(-z) + score + select + rescore + gather ---
__global__ __launch_bounds__(1024) void vq_fused(const float* __restrict__ z,
                                                 const _Float16* __restrict__ Bp,
                                                 const float* __restrict__ cb,
                                                 const float* __restrict__ csq,
                                                 float* __restrict__ zq,
                                                 float* __restrict__ outIdx) {
    __shared__ __align__(16) _Float16 Ah[64 * 256];   // 32 KB fragment-order (-z)
    __shared__ uint2 red[16][64];                     // 8 KB top-2 per tile/row

    const int tid  = threadIdx.x;
    const int lane = tid & 63;
    const int wv   = tid >> 6;            // 0..15
    // DIAGNOSTIC: blocks 256..511 replicate 0..255 (identical writes)
    const int rowBase = (blockIdx.x & 255) * 64;

    // ---- P1: stage 64 rows of -z as fp16 fragments, direct from global ----
#pragma unroll
    for (int i = 0; i < 2; ++i) {
        const int slot = i * 1024 + tid;  // 0..2047
        const int l  = slot & 63;
        const int g  = slot >> 6;         // 0..31 = m*8 + kt
        const int m  = g >> 3;
        const int kt = g & 7;
        const int row = rowBase + m * 16 + (l & 15);
        const int k0  = kt * 32 + (l >> 4) * 8;
        const float4 v0 = *reinterpret_cast<const float4*>(z + (size_t)row * DDIM + k0);
        const float4 v1 = *reinterpret_cast<const float4*>(z + (size_t)row * DDIM + k0 + 4);
        half8 h;
        h[0] = (_Float16)(-v0.x); h[1] = (_Float16)(-v0.y);
        h[2] = (_Float16)(-v0.z); h[3] = (_Float16)(-v0.w);
        h[4] = (_Float16)(-v1.x); h[5] = (_Float16)(-v1.y);
        h[6] = (_Float16)(-v1.z); h[7] = (_Float16)(-v1.w);
        *reinterpret_cast<half8*>(&Ah[g * 512 + l * 8]) = h;
    }
    __syncthreads();

    // ---- P2: MFMA (acc = 0.5*csq - dot) for colTile wv ----
    const half8* __restrict__ B = reinterpret_cast<const half8*>(Bp);
    const int cx = lane & 15;
    const int q  = lane >> 4;
    const int colTile = wv;               // 0..15
    const int colBase = colTile * 64;

    unsigned idxv[4];
    float    bias[4];
#pragma unroll
    for (int n = 0; n < 4; ++n) {
        idxv[n] = (unsigned)(colBase + n * 16 + cx);
        bias[n] = 0.5f * csq[idxv[n]];
    }

    f32x4 acc[4][4];
#pragma unroll
    for (int m = 0; m < 4; ++m)
#pragma unroll
        for (int n = 0; n < 4; ++n)
            acc[m][n] = (f32x4){bias[n], bias[n], bias[n], bias[n]};

#pragma unroll
    for (int kt = 0; kt < 8; ++kt) {
        half8 a[4], b[4];
#pragma unroll
        for (int m = 0; m < 4; ++m)
            a[m] = *reinterpret_cast<const half8*>(&Ah[(m * 8 + kt) * 512 + lane * 8]);
#pragma unroll
        for (int n = 0; n < 4; ++n)
            b[n] = B[(size_t)(((colTile * 4 + n) * 8 + kt) * 64 + lane)];
#pragma unroll
        for (int m = 0; m < 4; ++m)
#pragma unroll
            for (int n = 0; n < 4; ++n)
                acc[m][n] = __builtin_amdgcn_mfma_f32_16x16x32_f16(a[m], b[n], acc[m][n], 0, 0, 0);
    }

    // epilogue: key = (bits(acc) & ~1023) | idx ; top-2 via min/max nets
#pragma unroll
    for (int m = 0; m < 4; ++m)
#pragma unroll
        for (int r = 0; r < 4; ++r) {
            const unsigned ka = (__float_as_uint(acc[m][0][r]) & 0xFFFFFC00u) | idxv[0];
            const unsigned kb = (__float_as_uint(acc[m][1][r]) & 0xFFFFFC00u) | idxv[1];
            const unsigned kc = (__float_as_uint(acc[m][2][r]) & 0xFFFFFC00u) | idxv[2];
            const unsigned kd = (__float_as_uint(acc[m][3][r]) & 0xFFFFFC00u) | idxv[3];
            const unsigned m1 = umin2(ka, kb), M1 = umax2(ka, kb);
            const unsigned m2 = umin2(kc, kd), M2 = umax2(kc, kd);
            unsigned k0 = umin2(m1, m2);
            unsigned k1 = umin2(umax2(m1, m2), umin2(M1, M2));
            top2_merge(k0, k1, DPP_SELF(k0, 0x111), DPP_SELF(k1, 0x111));
            top2_merge(k0, k1, DPP_SELF(k0, 0x112), DPP_SELF(k1, 0x112));
            top2_merge(k0, k1, DPP_SELF(k0, 0x114), DPP_SELF(k1, 0x114));
            top2_merge(k0, k1, DPP_SELF(k0, 0x118), DPP_SELF(k1, 0x118));
            if (cx == 15) red[colTile][m * 16 + q * 4 + r] = make_uint2(k0, k1);
        }
    __syncthreads();

    // ---- P3: 4 rows/wave; merge -> 8 cands; margin test; rescore ----
#pragma unroll 1
    for (int i = 0; i < 4; ++i) {
        const int rl  = wv * 4 + i;
        const int row = rowBase + rl;

        unsigned kk[8];
#pragma unroll
        for (int g4 = 0; g4 < 4; ++g4) {
            const uint2 p0 = red[g4 * 4 + 0][rl], p1 = red[g4 * 4 + 1][rl];
            const uint2 p2 = red[g4 * 4 + 2][rl], p3 = red[g4 * 4 + 3][rl];
            unsigned a0 = p0.x, a1 = p0.y;
            top2_merge(a0, a1, p1.x, p1.y);
            unsigned b0 = p2.x, b1 = p2.y;
            top2_merge(b0, b1, p3.x, p3.y);
            top2_merge(a0, a1, b0, b1);
            kk[2 * g4] = a0; kk[2 * g4 + 1] = a1;
        }

        // global approx top-2 + margin (uniform across lanes)
        unsigned m0 = kk[0], m1 = kk[1];
        top2_merge(m0, m1, kk[2], kk[3]);
        top2_merge(m0, m1, kk[4], kk[5]);
        top2_merge(m0, m1, kk[6], kk[7]);
        const float s0 = __uint_as_float(m0 & 0xFFFFFC00u);   // 0.5*score
        const float s1 = __uint_as_float(m1 & 0xFFFFFC00u);

        if (s1 - s0 > 0.08f) {
            const int bI = (int)(m0 & 1023u);
            if (lane == 0) outIdx[row] = (float)bI;
            const float4 q4 = *reinterpret_cast<const float4*>(cb + (size_t)bI * DDIM + lane * 4);
            *reinterpret_cast<float4*>(zq + (size_t)row * DDIM + lane * 4) = q4;
            continue;
        }

        const float4 zv = *reinterpret_cast<const float4*>(z + (size_t)row * DDIM + lane * 4);

        const int idx0 = (int)(kk[0] & 1023u), idx1 = (int)(kk[1] & 1023u);
        const int idx2 = (int)(kk[2] & 1023u), idx3 = (int)(kk[3] & 1023u);
        const int idx4 = (int)(kk[4] & 1023u), idx5 = (int)(kk[5] & 1023u);
        const int idx6 = (int)(kk[6] & 1023u), idx7 = (int)(kk[7] & 1023u);
        const float4 cv0 = *reinterpret_cast<const float4*>(cb + (size_t)idx0 * DDIM + lane * 4);
        const float4 cv1 = *reinterpret_cast<const float4*>(cb + (size_t)idx1 * DDIM + lane * 4);
        const float4 cv2 = *reinterpret_cast<const float4*>(cb + (size_t)idx2 * DDIM + lane * 4);
        const float4 cv3 = *reinterpret_cast<const float4*>(cb + (size_t)idx3 * DDIM + lane * 4);
        const float4 cv4 = *reinterpret_cast<const float4*>(cb + (size_t)idx4 * DDIM + lane * 4);
        const float4 cv5 = *reinterpret_cast<const float4*>(cb + (size_t)idx5 * DDIM + lane * 4);
        const float4 cv6 = *reinterpret_cast<const float4*>(cb + (size_t)idx6 * DDIM + lane * 4);
        const float4 cv7 = *reinterpret_cast<const float4*>(cb + (size_t)idx7 * DDIM + lane * 4);

#define DOT4(cv) fmaf(zv.x, (cv).x, fmaf(zv.y, (cv).y, fmaf(zv.z, (cv).z, zv.w * (cv).w)))
        float p0 = DOT4(cv0), p1 = DOT4(cv1), p2 = DOT4(cv2), p3 = DOT4(cv3);
        float p4 = DOT4(cv4), p5 = DOT4(cv5), p6 = DOT4(cv6), p7 = DOT4(cv7);
#undef DOT4

        p0 = dpp_radd(p0); p1 = dpp_radd(p1); p2 = dpp_radd(p2); p3 = dpp_radd(p3);
        p4 = dpp_radd(p4); p5 = dpp_radd(p5); p6 = dpp_radd(p6); p7 = dpp_radd(p7);

        float bestS = fmaf(-2.0f, p0, csq[idx0]);
        int   bestI = idx0, bestC = 0;
#define CHECK(c, pc, ic)                                                     \
        {                                                                    \
            const float s = fmaf(-2.0f, (pc), csq[ic]);                      \
            const bool t = (s < bestS) || (s == bestS && (ic) < bestI);      \
            bestS = t ? s : bestS; bestI = t ? (ic) : bestI; bestC = t ? (c) : bestC; \
        }
        CHECK(1, p1, idx1) CHECK(2, p2, idx2) CHECK(3, p3, idx3)
        CHECK(4, p4, idx4) CHECK(5, p5, idx5) CHECK(6, p6, idx6) CHECK(7, p7, idx7)
#undef CHECK

        const int bI = __builtin_amdgcn_readlane(bestI, 63);
        const int bC = __builtin_amdgcn_readlane(bestC, 63);

        if (lane == 0) outIdx[row] = (float)bI;

        float4 q4 = cv0;
        if (bC == 1) q4 = cv1;
        if (bC == 2) q4 = cv2;
        if (bC == 3) q4 = cv3;
        if (bC == 4) q4 = cv4;
        if (bC == 5) q4 = cv5;
        if (bC == 6) q4 = cv6;
        if (bC == 7) q4 = cv7;
        *reinterpret_cast<float4*>(zq + (size_t)row * DDIM + lane * 4) = q4;
    }
}

extern "C" void kernel_launch(void* const* d_in, const int* in_sizes, int n_in,
                              void* d_out, int out_size, void* d_ws, size_t ws_size,
                              hipStream_t stream) {
    const float* z  = (const float*)d_in[0];   // [16384,256]
    const float* cb = (const float*)d_in[1];   // [1024,256]
    float* out    = (float*)d_out;
    float* zq     = out;                            // 16.77 MB
    float* outIdx = out + (size_t)M_ROWS * DDIM;    // 64 KB

    char* ws = (char*)d_ws;
    _Float16* chp = (_Float16*)ws;                  // 512 KB
    float* csq    = (float*)(ws + 512 * 1024);      // 4 KB

    vq_prep_cb<<<384, 256, 0, stream>>>(cb, chp, csq);
    // DIAGNOSTIC grid x2: second half replicates first (identical writes)
    vq_fused<<<(M_ROWS / 64) * 2, 1024, 0, stream>>>(z, chp, cb, csq, zq, outIdx);
}

// Round 22
// 33.540 us; speedup vs baseline: 1.3918x; 1.3918x over previous
//
#include <hip/hip_runtime.h>

// VectorQuantizer: fused (pack + fp16-MFMA filter + exact fp32 rescore).
// z_e [16,1024,256] f32, codebook [1024,256] f32
// out = concat( z_q [16,1024,256] f32 , indices [16,1024] as f32 )
//
// R22 = R19 selection/structure at 32 rows/block, 512 blocks x 1024 thr:
//  * 2 blocks/CU co-resident (20 KB LDS, ~96 reg/wave) = 32 waves/CU —
//    R21's counters showed latency-bound with no saturated pipe and 76%
//    marginal efficiency for a 2nd co-resident block's worth of waves.
//  * per-thread VALU ~halved (epilogue 8 (m,r) pairs; P3 2 rows/wave).
//  * P1 stages -z as fp16 fragments (1 granule-slot/thread).
//  * MFMA acc init = +0.5*csq[col] -> acc = 0.5*score >= 0 ->
//    key = (bits(acc) & ~1023) | idx; top-2 via v_min/v_max networks.
//  * P3 early-exit: margin (half-scale) > 0.08 -> winner provably exact.
//  * __launch_bounds__(1024) ONLY — arg2 clamps VGPR to 64 (measured).

#define M_ROWS 16384
#define DDIM   256
#define NCODES 1024
#define ROWS   32

typedef _Float16 half8 __attribute__((ext_vector_type(8)));
typedef float    f32x4 __attribute__((ext_vector_type(4)));

__device__ __forceinline__ unsigned umin2(unsigned a, unsigned b) { return a < b ? a : b; }
__device__ __forceinline__ unsigned umax2(unsigned a, unsigned b) { return a > b ? a : b; }
__device__ __forceinline__ void top2_merge(unsigned& k0, unsigned& k1,
                                           unsigned o0, unsigned o1) {
    const unsigned t = umax2(k0, o0);
    k0 = umin2(k0, o0);
    k1 = umin2(t, umin2(k1, o1));
}

#define DPP_SELF(k, ctrl) \
    ((unsigned)__builtin_amdgcn_update_dpp((int)(k), (int)(k), (ctrl), 0xF, 0xF, false))
#define DPP_Z(v, ctrl) \
    __builtin_amdgcn_update_dpp(0, (v), (ctrl), 0xF, 0xF, true)

// 64-lane sum via DPP; total valid in lane 63
__device__ __forceinline__ float dpp_radd(float x) {
    float s = x;
    s += __int_as_float(DPP_Z(__float_as_int(s), 0x111));
    s += __int_as_float(DPP_Z(__float_as_int(s), 0x112));
    s += __int_as_float(DPP_Z(__float_as_int(s), 0x114));
    s += __int_as_float(DPP_Z(__float_as_int(s), 0x118));
    s += __int_as_float(DPP_Z(__float_as_int(s), 0x142));
    s += __int_as_float(DPP_Z(__float_as_int(s), 0x143));
    return s;
}

// ---------------- K1: pack cb (blocks 0..127) + csq (blocks 128..383) ------
__global__ __launch_bounds__(256) void vq_prep_cb(const float* __restrict__ cb,
                                                  _Float16* __restrict__ chp,
                                                  float* __restrict__ csq) {
    if (blockIdx.x < 128) {
        const int gid = blockIdx.x * 256 + threadIdx.x;
        const int l   = gid & 63;
        const int g   = gid >> 6;
        const int kt  = g & 7;
        const int rt  = g >> 3;
        const int row = rt * 16 + (l & 15);
        const int k0  = kt * 32 + (l >> 4) * 8;
        const float4 v0 = *reinterpret_cast<const float4*>(cb + (size_t)row * DDIM + k0);
        const float4 v1 = *reinterpret_cast<const float4*>(cb + (size_t)row * DDIM + k0 + 4);
        half8 h;
        h[0] = (_Float16)v0.x; h[1] = (_Float16)v0.y; h[2] = (_Float16)v0.z; h[3] = (_Float16)v0.w;
        h[4] = (_Float16)v1.x; h[5] = (_Float16)v1.y; h[6] = (_Float16)v1.z; h[7] = (_Float16)v1.w;
        *reinterpret_cast<half8*>(chp + (size_t)gid * 8) = h;
    } else {
        const int code = (blockIdx.x - 128) * 4 + (threadIdx.x >> 6);
        const int lane = threadIdx.x & 63;
        const float4 v = *reinterpret_cast<const float4*>(cb + (size_t)code * DDIM + lane * 4);
        float s = v.x * v.x + v.y * v.y + v.z * v.z + v.w * v.w;
        s = dpp_radd(s);
        if (lane == 63) csq[code] = s;
    }
}

// ---------------- K2: fused pack(-z) + score + select + rescore + gather ---
__global__ __launch_bounds__(1024) void vq_fused(const float* __restrict__ z,
                                                 const _Float16* __restrict__ Bp,
                                                 const float* __restrict__ cb,
                                                 const float* __restrict__ csq,
                                                 float* __restrict__ zq,
                                                 float* __restrict__ outIdx) {
    __shared__ __align__(16) _Float16 Ah[ROWS * 256];   // 16 KB fragment-order (-z)
    __shared__ uint2 red[16][ROWS];                     // 4 KB top-2 per tile/row

    const int tid  = threadIdx.x;
    const int lane = tid & 63;
    const int wv   = tid >> 6;            // 0..15
    const int rowBase = blockIdx.x * ROWS;

    // ---- P1: stage 32 rows of -z as fp16 fragments (1 slot/thread) ----
    {
        const int l  = tid & 63;
        const int g  = tid >> 6;          // 0..15 = m*8 + kt
        const int m  = g >> 3;            // 0..1
        const int kt = g & 7;
        const int row = rowBase + m * 16 + (l & 15);
        const int k0  = kt * 32 + (l >> 4) * 8;
        const float4 v0 = *reinterpret_cast<const float4*>(z + (size_t)row * DDIM + k0);
        const float4 v1 = *reinterpret_cast<const float4*>(z + (size_t)row * DDIM + k0 + 4);
        half8 h;
        h[0] = (_Float16)(-v0.x); h[1] = (_Float16)(-v0.y);
        h[2] = (_Float16)(-v0.z); h[3] = (_Float16)(-v0.w);
        h[4] = (_Float16)(-v1.x); h[5] = (_Float16)(-v1.y);
        h[6] = (_Float16)(-v1.z); h[7] = (_Float16)(-v1.w);
        *reinterpret_cast<half8*>(&Ah[g * 512 + l * 8]) = h;
    }
    __syncthreads();

    // ---- P2: MFMA (acc = 0.5*csq - dot) for colTile wv ----
    const half8* __restrict__ B = reinterpret_cast<const half8*>(Bp);
    const int cx = lane & 15;
    const int q  = lane >> 4;
    const int colTile = wv;               // 0..15
    const int colBase = colTile * 64;

    unsigned idxv[4];
    float    bias[4];
#pragma unroll
    for (int n = 0; n < 4; ++n) {
        idxv[n] = (unsigned)(colBase + n * 16 + cx);
        bias[n] = 0.5f * csq[idxv[n]];
    }

    f32x4 acc[2][4];
#pragma unroll
    for (int m = 0; m < 2; ++m)
#pragma unroll
        for (int n = 0; n < 4; ++n)
            acc[m][n] = (f32x4){bias[n], bias[n], bias[n], bias[n]};

#pragma unroll
    for (int kt = 0; kt < 8; ++kt) {
        half8 a[2], b[4];
#pragma unroll
        for (int m = 0; m < 2; ++m)
            a[m] = *reinterpret_cast<const half8*>(&Ah[(m * 8 + kt) * 512 + lane * 8]);
#pragma unroll
        for (int n = 0; n < 4; ++n)
            b[n] = B[(size_t)(((colTile * 4 + n) * 8 + kt) * 64 + lane)];
#pragma unroll
        for (int m = 0; m < 2; ++m)
#pragma unroll
            for (int n = 0; n < 4; ++n)
                acc[m][n] = __builtin_amdgcn_mfma_f32_16x16x32_f16(a[m], b[n], acc[m][n], 0, 0, 0);
    }

    // epilogue: key = (bits(acc) & ~1023) | idx ; top-2 via min/max nets
#pragma unroll
    for (int m = 0; m < 2; ++m)
#pragma unroll
        for (int r = 0; r < 4; ++r) {
            const unsigned ka = (__float_as_uint(acc[m][0][r]) & 0xFFFFFC00u) | idxv[0];
            const unsigned kb = (__float_as_uint(acc[m][1][r]) & 0xFFFFFC00u) | idxv[1];
            const unsigned kc = (__float_as_uint(acc[m][2][r]) & 0xFFFFFC00u) | idxv[2];
            const unsigned kd = (__float_as_uint(acc[m][3][r]) & 0xFFFFFC00u) | idxv[3];
            const unsigned m1 = umin2(ka, kb), M1 = umax2(ka, kb);
            const unsigned m2 = umin2(kc, kd), M2 = umax2(kc, kd);
            unsigned k0 = umin2(m1, m2);
            unsigned k1 = umin2(umax2(m1, m2), umin2(M1, M2));
            top2_merge(k0, k1, DPP_SELF(k0, 0x111), DPP_SELF(k1, 0x111));
            top2_merge(k0, k1, DPP_SELF(k0, 0x112), DPP_SELF(k1, 0x112));
            top2_merge(k0, k1, DPP_SELF(k0, 0x114), DPP_SELF(k1, 0x114));
            top2_merge(k0, k1, DPP_SELF(k0, 0x118), DPP_SELF(k1, 0x118));
            if (cx == 15) red[colTile][m * 16 + q * 4 + r] = make_uint2(k0, k1);
        }
    __syncthreads();

    // ---- P3: 2 rows/wave; merge -> 8 cands; margin test; rescore ----
#pragma unroll 1
    for (int i = 0; i < 2; ++i) {
        const int rl  = wv * 2 + i;
        const int row = rowBase + rl;

        unsigned kk[8];
#pragma unroll
        for (int g4 = 0; g4 < 4; ++g4) {
            const uint2 p0 = red[g4 * 4 + 0][rl], p1 = red[g4 * 4 + 1][rl];
            const uint2 p2 = red[g4 * 4 + 2][rl], p3 = red[g4 * 4 + 3][rl];
            unsigned a0 = p0.x, a1 = p0.y;
            top2_merge(a0, a1, p1.x, p1.y);
            unsigned b0 = p2.x, b1 = p2.y;
            top2_merge(b0, b1, p3.x, p3.y);
            top2_merge(a0, a1, b0, b1);
            kk[2 * g4] = a0; kk[2 * g4 + 1] = a1;
        }

        // global approx top-2 + margin (uniform across lanes)
        unsigned m0 = kk[0], m1 = kk[1];
        top2_merge(m0, m1, kk[2], kk[3]);
        top2_merge(m0, m1, kk[4], kk[5]);
        top2_merge(m0, m1, kk[6], kk[7]);
        const float s0 = __uint_as_float(m0 & 0xFFFFFC00u);   // 0.5*score
        const float s1 = __uint_as_float(m1 & 0xFFFFFC00u);

        if (s1 - s0 > 0.08f) {
            const int bI = (int)(m0 & 1023u);
            if (lane == 0) outIdx[row] = (float)bI;
            const float4 q4 = *reinterpret_cast<const float4*>(cb + (size_t)bI * DDIM + lane * 4);
            *reinterpret_cast<float4*>(zq + (size_t)row * DDIM + lane * 4) = q4;
            continue;
        }

        const float4 zv = *reinterpret_cast<const float4*>(z + (size_t)row * DDIM + lane * 4);

        const int idx0 = (int)(kk[0] & 1023u), idx1 = (int)(kk[1] & 1023u);
        const int idx2 = (int)(kk[2] & 1023u), idx3 = (int)(kk[3] & 1023u);
        const int idx4 = (int)(kk[4] & 1023u), idx5 = (int)(kk[5] & 1023u);
        const int idx6 = (int)(kk[6] & 1023u), idx7 = (int)(kk[7] & 1023u);
        const float4 cv0 = *reinterpret_cast<const float4*>(cb + (size_t)idx0 * DDIM + lane * 4);
        const float4 cv1 = *reinterpret_cast<const float4*>(cb + (size_t)idx1 * DDIM + lane * 4);
        const float4 cv2 = *reinterpret_cast<const float4*>(cb + (size_t)idx2 * DDIM + lane * 4);
        const float4 cv3 = *reinterpret_cast<const float4*>(cb + (size_t)idx3 * DDIM + lane * 4);
        const float4 cv4 = *reinterpret_cast<const float4*>(cb + (size_t)idx4 * DDIM + lane * 4);
        const float4 cv5 = *reinterpret_cast<const float4*>(cb + (size_t)idx5 * DDIM + lane * 4);
        const float4 cv6 = *reinterpret_cast<const float4*>(cb + (size_t)idx6 * DDIM + lane * 4);
        const float4 cv7 = *reinterpret_cast<const float4*>(cb + (size_t)idx7 * DDIM + lane * 4);

#define DOT4(cv) fmaf(zv.x, (cv).x, fmaf(zv.y, (cv).y, fmaf(zv.z, (cv).z, zv.w * (cv).w)))
        float p0 = DOT4(cv0), p1 = DOT4(cv1), p2 = DOT4(cv2), p3 = DOT4(cv3);
        float p4 = DOT4(cv4), p5 = DOT4(cv5), p6 = DOT4(cv6), p7 = DOT4(cv7);
#undef DOT4

        p0 = dpp_radd(p0); p1 = dpp_radd(p1); p2 = dpp_radd(p2); p3 = dpp_radd(p3);
        p4 = dpp_radd(p4); p5 = dpp_radd(p5); p6 = dpp_radd(p6); p7 = dpp_radd(p7);

        float bestS = fmaf(-2.0f, p0, csq[idx0]);
        int   bestI = idx0, bestC = 0;
#define CHECK(c, pc, ic)                                                     \
        {                                                                    \
            const float s = fmaf(-2.0f, (pc), csq[ic]);                      \
            const bool t = (s < bestS) || (s == bestS && (ic) < bestI);      \
            bestS = t ? s : bestS; bestI = t ? (ic) : bestI; bestC = t ? (c) : bestC; \
        }
        CHECK(1, p1, idx1) CHECK(2, p2, idx2) CHECK(3, p3, idx3)
        CHECK(4, p4, idx4) CHECK(5, p5, idx5) CHECK(6, p6, idx6) CHECK(7, p7, idx7)
#undef CHECK

        const int bI = __builtin_amdgcn_readlane(bestI, 63);
        const int bC = __builtin_amdgcn_readlane(bestC, 63);

        if (lane == 0) outIdx[row] = (float)bI;

        float4 q4 = cv0;
        if (bC == 1) q4 = cv1;
        if (bC == 2) q4 = cv2;
        if (bC == 3) q4 = cv3;
        if (bC == 4) q4 = cv4;
        if (bC == 5) q4 = cv5;
        if (bC == 6) q4 = cv6;
        if (bC == 7) q4 = cv7;
        *reinterpret_cast<float4*>(zq + (size_t)row * DDIM + lane * 4) = q4;
    }
}

extern "C" void kernel_launch(void* const* d_in, const int* in_sizes, int n_in,
                              void* d_out, int out_size, void* d_ws, size_t ws_size,
                              hipStream_t stream) {
    const float* z  = (const float*)d_in[0];   // [16384,256]
    const float* cb = (const float*)d_in[1];   // [1024,256]
    float* out    = (float*)d_out;
    float* zq     = out;                            // 16.77 MB
    float* outIdx = out + (size_t)M_ROWS * DDIM;    // 64 KB

    char* ws = (char*)d_ws;
    _Float16* chp = (_Float16*)ws;                  // 512 KB
    float* csq    = (float*)(ws + 512 * 1024);      // 4 KB

    vq_prep_cb<<<384, 256, 0, stream>>>(cb, chp, csq);
    vq_fused<<<M_ROWS / ROWS, 1024, 0, stream>>>(z, chp, cb, csq, zq, outIdx);
}

// Round 23
// 30.271 us; speedup vs baseline: 1.5422x; 1.1080x over previous
//
#include <hip/hip_runtime.h>

// VectorQuantizer: fused (pack + fp16-MFMA filter + exact fp32 rescore).
// z_e [16,1024,256] f32, codebook [1024,256] f32
// out = concat( z_q [16,1024,256] f32 , indices [16,1024] as f32 )
//
// R23 = R19 EXACT fused kernel (best measured, 30.3us) + z L3-prewarm
// folded into the prep kernel (blocks 384..895 stream z; dump-store keeps
// the loads live). Mechanism: R21 counters showed the fused kernel is
// latency-bound and its warm-cache repeat pass ran ~20% faster — P1's
// cold HBM z-read (~900cy) is part of the exposed stall; prewarming to
// L3 (~300cy) shaves it. Fused kernel untouched -> worst case ~30.3.
//
//  * 256 blocks x 1024 thr (16 waves/CU), 64 rows/block, 40 KB LDS,
//    B swept once per block; wave = one 64-code colTile, acc[4][4].
//  * MFMA acc init = +0.5*csq[col] -> acc = 0.5*score >= 0 ->
//    key = (bits(acc) & ~1023) | idx; top-2 via v_min/v_max networks.
//  * P3 early-exit: margin (half-scale) > 0.08 -> winner provably exact.
//  * __launch_bounds__ arg2 never used (clamps VGPR to 64 -> spills).

#define M_ROWS 16384
#define DDIM   256
#define NCODES 1024

typedef _Float16 half8 __attribute__((ext_vector_type(8)));
typedef float    f32x4 __attribute__((ext_vector_type(4)));

__device__ __forceinline__ unsigned umin2(unsigned a, unsigned b) { return a < b ? a : b; }
__device__ __forceinline__ unsigned umax2(unsigned a, unsigned b) { return a > b ? a : b; }
__device__ __forceinline__ void top2_merge(unsigned& k0, unsigned& k1,
                                           unsigned o0, unsigned o1) {
    const unsigned t = umax2(k0, o0);
    k0 = umin2(k0, o0);
    k1 = umin2(t, umin2(k1, o1));
}

#define DPP_SELF(k, ctrl) \
    ((unsigned)__builtin_amdgcn_update_dpp((int)(k), (int)(k), (ctrl), 0xF, 0xF, false))
#define DPP_Z(v, ctrl) \
    __builtin_amdgcn_update_dpp(0, (v), (ctrl), 0xF, 0xF, true)

// 64-lane sum via DPP; total valid in lane 63
__device__ __forceinline__ float dpp_radd(float x) {
    float s = x;
    s += __int_as_float(DPP_Z(__float_as_int(s), 0x111));
    s += __int_as_float(DPP_Z(__float_as_int(s), 0x112));
    s += __int_as_float(DPP_Z(__float_as_int(s), 0x114));
    s += __int_as_float(DPP_Z(__float_as_int(s), 0x118));
    s += __int_as_float(DPP_Z(__float_as_int(s), 0x142));
    s += __int_as_float(DPP_Z(__float_as_int(s), 0x143));
    return s;
}

// ---- K1: pack cb (blocks 0..127) + csq (128..383) + z prewarm (384..895) --
__global__ __launch_bounds__(256) void vq_prep_cb(const float* __restrict__ cb,
                                                  const float* __restrict__ z,
                                                  _Float16* __restrict__ chp,
                                                  float* __restrict__ csq,
                                                  float* __restrict__ dump) {
    if (blockIdx.x < 128) {
        const int gid = blockIdx.x * 256 + threadIdx.x;
        const int l   = gid & 63;
        const int g   = gid >> 6;
        const int kt  = g & 7;
        const int rt  = g >> 3;
        const int row = rt * 16 + (l & 15);
        const int k0  = kt * 32 + (l >> 4) * 8;
        const float4 v0 = *reinterpret_cast<const float4*>(cb + (size_t)row * DDIM + k0);
        const float4 v1 = *reinterpret_cast<const float4*>(cb + (size_t)row * DDIM + k0 + 4);
        half8 h;
        h[0] = (_Float16)v0.x; h[1] = (_Float16)v0.y; h[2] = (_Float16)v0.z; h[3] = (_Float16)v0.w;
        h[4] = (_Float16)v1.x; h[5] = (_Float16)v1.y; h[6] = (_Float16)v1.z; h[7] = (_Float16)v1.w;
        *reinterpret_cast<half8*>(chp + (size_t)gid * 8) = h;
    } else if (blockIdx.x < 384) {
        const int code = (blockIdx.x - 128) * 4 + (threadIdx.x >> 6);
        const int lane = threadIdx.x & 63;
        const float4 v = *reinterpret_cast<const float4*>(cb + (size_t)code * DDIM + lane * 4);
        float s = v.x * v.x + v.y * v.y + v.z * v.z + v.w * v.w;
        s = dpp_radd(s);
        if (lane == 63) csq[code] = s;
    } else {
        // z prewarm: stream 16.8 MB through L2/L3; dump keeps loads live
        const int b = blockIdx.x - 384;           // 0..511
        const float4* zp = reinterpret_cast<const float4*>(z) +
                           (size_t)b * 2048 + threadIdx.x;
        float s = 0.0f;
#pragma unroll
        for (int i = 0; i < 8; ++i) {
            const float4 v = zp[i * 256];
            s += v.x + v.y + v.z + v.w;
        }
        if (threadIdx.x == 0) dump[b] = s;
    }
}

// ---------------- K2: fused pack(-z) + score + select + rescore + gather ---
__global__ __launch_bounds__(1024) void vq_fused(const float* __restrict__ z,
                                                 const _Float16* __restrict__ Bp,
                                                 const float* __restrict__ cb,
                                                 const float* __restrict__ csq,
                                                 float* __restrict__ zq,
                                                 float* __restrict__ outIdx) {
    __shared__ __align__(16) _Float16 Ah[64 * 256];   // 32 KB fragment-order (-z)
    __shared__ uint2 red[16][64];                     // 8 KB top-2 per tile/row

    const int tid  = threadIdx.x;
    const int lane = tid & 63;
    const int wv   = tid >> 6;            // 0..15
    const int rowBase = blockIdx.x * 64;

    // ---- P1: stage 64 rows of -z as fp16 fragments, direct from global ----
#pragma unroll
    for (int i = 0; i < 2; ++i) {
        const int slot = i * 1024 + tid;  // 0..2047
        const int l  = slot & 63;
        const int g  = slot >> 6;         // 0..31 = m*8 + kt
        const int m  = g >> 3;
        const int kt = g & 7;
        const int row = rowBase + m * 16 + (l & 15);
        const int k0  = kt * 32 + (l >> 4) * 8;
        const float4 v0 = *reinterpret_cast<const float4*>(z + (size_t)row * DDIM + k0);
        const float4 v1 = *reinterpret_cast<const float4*>(z + (size_t)row * DDIM + k0 + 4);
        half8 h;
        h[0] = (_Float16)(-v0.x); h[1] = (_Float16)(-v0.y);
        h[2] = (_Float16)(-v0.z); h[3] = (_Float16)(-v0.w);
        h[4] = (_Float16)(-v1.x); h[5] = (_Float16)(-v1.y);
        h[6] = (_Float16)(-v1.z); h[7] = (_Float16)(-v1.w);
        *reinterpret_cast<half8*>(&Ah[g * 512 + l * 8]) = h;
    }
    __syncthreads();

    // ---- P2: MFMA (acc = 0.5*csq - dot) for colTile wv ----
    const half8* __restrict__ B = reinterpret_cast<const half8*>(Bp);
    const int cx = lane & 15;
    const int q  = lane >> 4;
    const int colTile = wv;               // 0..15
    const int colBase = colTile * 64;

    unsigned idxv[4];
    float    bias[4];
#pragma unroll
    for (int n = 0; n < 4; ++n) {
        idxv[n] = (unsigned)(colBase + n * 16 + cx);
        bias[n] = 0.5f * csq[idxv[n]];
    }

    f32x4 acc[4][4];
#pragma unroll
    for (int m = 0; m < 4; ++m)
#pragma unroll
        for (int n = 0; n < 4; ++n)
            acc[m][n] = (f32x4){bias[n], bias[n], bias[n], bias[n]};

#pragma unroll
    for (int kt = 0; kt < 8; ++kt) {
        half8 a[4], b[4];
#pragma unroll
        for (int m = 0; m < 4; ++m)
            a[m] = *reinterpret_cast<const half8*>(&Ah[(m * 8 + kt) * 512 + lane * 8]);
#pragma unroll
        for (int n = 0; n < 4; ++n)
            b[n] = B[(size_t)(((colTile * 4 + n) * 8 + kt) * 64 + lane)];
#pragma unroll
        for (int m = 0; m < 4; ++m)
#pragma unroll
            for (int n = 0; n < 4; ++n)
                acc[m][n] = __builtin_amdgcn_mfma_f32_16x16x32_f16(a[m], b[n], acc[m][n], 0, 0, 0);
    }

    // epilogue: key = (bits(acc) & ~1023) | idx ; top-2 via min/max nets
#pragma unroll
    for (int m = 0; m < 4; ++m)
#pragma unroll
        for (int r = 0; r < 4; ++r) {
            const unsigned ka = (__float_as_uint(acc[m][0][r]) & 0xFFFFFC00u) | idxv[0];
            const unsigned kb = (__float_as_uint(acc[m][1][r]) & 0xFFFFFC00u) | idxv[1];
            const unsigned kc = (__float_as_uint(acc[m][2][r]) & 0xFFFFFC00u) | idxv[2];
            const unsigned kd = (__float_as_uint(acc[m][3][r]) & 0xFFFFFC00u) | idxv[3];
            const unsigned m1 = umin2(ka, kb), M1 = umax2(ka, kb);
            const unsigned m2 = umin2(kc, kd), M2 = umax2(kc, kd);
            unsigned k0 = umin2(m1, m2);
            unsigned k1 = umin2(umax2(m1, m2), umin2(M1, M2));
            top2_merge(k0, k1, DPP_SELF(k0, 0x111), DPP_SELF(k1, 0x111));
            top2_merge(k0, k1, DPP_SELF(k0, 0x112), DPP_SELF(k1, 0x112));
            top2_merge(k0, k1, DPP_SELF(k0, 0x114), DPP_SELF(k1, 0x114));
            top2_merge(k0, k1, DPP_SELF(k0, 0x118), DPP_SELF(k1, 0x118));
            if (cx == 15) red[colTile][m * 16 + q * 4 + r] = make_uint2(k0, k1);
        }
    __syncthreads();

    // ---- P3: 4 rows/wave; merge -> 8 cands; margin test; rescore ----
#pragma unroll 1
    for (int i = 0; i < 4; ++i) {
        const int rl  = wv * 4 + i;
        const int row = rowBase + rl;

        unsigned kk[8];
#pragma unroll
        for (int g4 = 0; g4 < 4; ++g4) {
            const uint2 p0 = red[g4 * 4 + 0][rl], p1 = red[g4 * 4 + 1][rl];
            const uint2 p2 = red[g4 * 4 + 2][rl], p3 = red[g4 * 4 + 3][rl];
            unsigned a0 = p0.x, a1 = p0.y;
            top2_merge(a0, a1, p1.x, p1.y);
            unsigned b0 = p2.x, b1 = p2.y;
            top2_merge(b0, b1, p3.x, p3.y);
            top2_merge(a0, a1, b0, b1);
            kk[2 * g4] = a0; kk[2 * g4 + 1] = a1;
        }

        // global approx top-2 + margin (uniform across lanes)
        unsigned m0 = kk[0], m1 = kk[1];
        top2_merge(m0, m1, kk[2], kk[3]);
        top2_merge(m0, m1, kk[4], kk[5]);
        top2_merge(m0, m1, kk[6], kk[7]);
        const float s0 = __uint_as_float(m0 & 0xFFFFFC00u);   // 0.5*score
        const float s1 = __uint_as_float(m1 & 0xFFFFFC00u);

        if (s1 - s0 > 0.08f) {
            const int bI = (int)(m0 & 1023u);
            if (lane == 0) outIdx[row] = (float)bI;
            const float4 q4 = *reinterpret_cast<const float4*>(cb + (size_t)bI * DDIM + lane * 4);
            *reinterpret_cast<float4*>(zq + (size_t)row * DDIM + lane * 4) = q4;
            continue;
        }

        const float4 zv = *reinterpret_cast<const float4*>(z + (size_t)row * DDIM + lane * 4);

        const int idx0 = (int)(kk[0] & 1023u), idx1 = (int)(kk[1] & 1023u);
        const int idx2 = (int)(kk[2] & 1023u), idx3 = (int)(kk[3] & 1023u);
        const int idx4 = (int)(kk[4] & 1023u), idx5 = (int)(kk[5] & 1023u);
        const int idx6 = (int)(kk[6] & 1023u), idx7 = (int)(kk[7] & 1023u);
        const float4 cv0 = *reinterpret_cast<const float4*>(cb + (size_t)idx0 * DDIM + lane * 4);
        const float4 cv1 = *reinterpret_cast<const float4*>(cb + (size_t)idx1 * DDIM + lane * 4);
        const float4 cv2 = *reinterpret_cast<const float4*>(cb + (size_t)idx2 * DDIM + lane * 4);
        const float4 cv3 = *reinterpret_cast<const float4*>(cb + (size_t)idx3 * DDIM + lane * 4);
        const float4 cv4 = *reinterpret_cast<const float4*>(cb + (size_t)idx4 * DDIM + lane * 4);
        const float4 cv5 = *reinterpret_cast<const float4*>(cb + (size_t)idx5 * DDIM + lane * 4);
        const float4 cv6 = *reinterpret_cast<const float4*>(cb + (size_t)idx6 * DDIM + lane * 4);
        const float4 cv7 = *reinterpret_cast<const float4*>(cb + (size_t)idx7 * DDIM + lane * 4);

#define DOT4(cv) fmaf(zv.x, (cv).x, fmaf(zv.y, (cv).y, fmaf(zv.z, (cv).z, zv.w * (cv).w)))
        float p0 = DOT4(cv0), p1 = DOT4(cv1), p2 = DOT4(cv2), p3 = DOT4(cv3);
        float p4 = DOT4(cv4), p5 = DOT4(cv5), p6 = DOT4(cv6), p7 = DOT4(cv7);
#undef DOT4

        p0 = dpp_radd(p0); p1 = dpp_radd(p1); p2 = dpp_radd(p2); p3 = dpp_radd(p3);
        p4 = dpp_radd(p4); p5 = dpp_radd(p5); p6 = dpp_radd(p6); p7 = dpp_radd(p7);

        float bestS = fmaf(-2.0f, p0, csq[idx0]);
        int   bestI = idx0, bestC = 0;
#define CHECK(c, pc, ic)                                                     \
        {                                                                    \
            const float s = fmaf(-2.0f, (pc), csq[ic]);                      \
            const bool t = (s < bestS) || (s == bestS && (ic) < bestI);      \
            bestS = t ? s : bestS; bestI = t ? (ic) : bestI; bestC = t ? (c) : bestC; \
        }
        CHECK(1, p1, idx1) CHECK(2, p2, idx2) CHECK(3, p3, idx3)
        CHECK(4, p4, idx4) CHECK(5, p5, idx5) CHECK(6, p6, idx6) CHECK(7, p7, idx7)
#undef CHECK

        const int bI = __builtin_amdgcn_readlane(bestI, 63);
        const int bC = __builtin_amdgcn_readlane(bestC, 63);

        if (lane == 0) outIdx[row] = (float)bI;

        float4 q4 = cv0;
        if (bC == 1) q4 = cv1;
        if (bC == 2) q4 = cv2;
        if (bC == 3) q4 = cv3;
        if (bC == 4) q4 = cv4;
        if (bC == 5) q4 = cv5;
        if (bC == 6) q4 = cv6;
        if (bC == 7) q4 = cv7;
        *reinterpret_cast<float4*>(zq + (size_t)row * DDIM + lane * 4) = q4;
    }
}

extern "C" void kernel_launch(void* const* d_in, const int* in_sizes, int n_in,
                              void* d_out, int out_size, void* d_ws, size_t ws_size,
                              hipStream_t stream) {
    const float* z  = (const float*)d_in[0];   // [16384,256]
    const float* cb = (const float*)d_in[1];   // [1024,256]
    float* out    = (float*)d_out;
    float* zq     = out;                            // 16.77 MB
    float* outIdx = out + (size_t)M_ROWS * DDIM;    // 64 KB

    char* ws = (char*)d_ws;
    _Float16* chp = (_Float16*)ws;                  // 512 KB
    float* csq    = (float*)(ws + 512 * 1024);      // 4 KB
    float* dump   = (float*)(ws + 1024 * 1024);     // 2 KB prewarm dump

    vq_prep_cb<<<896, 256, 0, stream>>>(cb, z, chp, csq, dump);
    vq_fused<<<M_ROWS / 64, 1024, 0, stream>>>(z, chp, cb, csq, zq, outIdx);
}